// Round 6
// baseline (138.791 us; speedup 1.0000x reference)
//
#include <hip/hip_runtime.h>
#include <hip/hip_bf16.h>

#define S_ 1024
#define D_ 64
#define QBLK 32
#define THREADS 256
#define LOG2E 1.44269504088896f

typedef __attribute__((ext_vector_type(8)))  short short8;
typedef __attribute__((ext_vector_type(4)))  int   int4v;
typedef __attribute__((ext_vector_type(16))) float f32x16;
typedef __attribute__((ext_vector_type(4)))  float f32x4;

__device__ __forceinline__ unsigned short f2bfu(float x) {
  return __builtin_bit_cast(unsigned short, __float2bfloat16(x));
}
__device__ __forceinline__ float bfu2f(unsigned short s) {
  return __builtin_bit_cast(float, (unsigned)s << 16);
}

// ---------------------------------------------------------------------------
// prep (unchanged from round 5):
//  [0,2048)     kb = bf16(k)
//  [2048,3072)  vp = bf16 V transposed+MFMA-permuted via padded LDS tile
//  [3072,5120)  mw bit-pack via wave ballot, grid-strided x8
// ---------------------------------------------------------------------------
__global__ __launch_bounds__(THREADS) void prep(
    const float* __restrict__ k, const float* __restrict__ v,
    const int* __restrict__ mask, short* __restrict__ kb,
    short* __restrict__ vp, unsigned* __restrict__ mw) {
  const int blk = blockIdx.x;
  const int tid = threadIdx.x;
  if (blk < 2048) {
    const int gid = blk * THREADS + tid;
    const int row = gid >> 3;
    const int c8 = (gid & 7) << 3;
    const float* src = k + (((size_t)row) << 6) + c8;
    f32x4 x0 = *(const f32x4*)src;
    f32x4 x1 = *(const f32x4*)(src + 4);
    short8 o;
#pragma unroll
    for (int i = 0; i < 4; ++i) {
      o[i] = (short)f2bfu(x0[i]);
      o[i + 4] = (short)f2bfu(x1[i]);
    }
    *(short8*)(kb + (((size_t)row) << 6) + c8) = o;
  } else if (blk < 3072) {
    __shared__ short vt[64 * 65];
    const int g = blk - 2048;
    const int bh = g >> 4;
    const int k0 = (g & 15) << 6;
    const int kl = tid >> 2;
    const int d0 = (tid & 3) << 4;
    const float* vsrc = v + ((((size_t)bh << 10) + k0 + kl) << 6) + d0;
#pragma unroll
    for (int c = 0; c < 4; ++c) {
      f32x4 x = *(const f32x4*)(vsrc + 4 * c);
      short* dst = &vt[kl * 65 + d0 + 4 * c];
#pragma unroll
      for (int i = 0; i < 4; ++i) dst[i] = (short)f2bfu(x[i]);
    }
    __syncthreads();
    const int d = tid >> 2;
    const int g2 = tid & 3;
    short8 w0, w1;
#pragma unroll
    for (int i = 0; i < 8; ++i) {
      const int klo = (g2 << 4) + (i & 3) + ((i >> 2) << 3);
      w0[i] = vt[klo * 65 + d];
      w1[i] = vt[(klo + 4) * 65 + d];
    }
    short* dst = vp + ((size_t)bh << 16) + ((size_t)d << 10) + k0 + (g2 << 4);
    *(short8*)dst = w0;
    *(short8*)(dst + 8) = w1;
  } else {
    const int g = blk - 3072;
#pragma unroll
    for (int it = 0; it < 8; ++it) {
      const size_t base = ((size_t)g * 8 + it) * THREADS + tid;
      const unsigned long long bal = __ballot(mask[base] != 0);
      if ((tid & 63) == 0) {
        const size_t w2 = base >> 5;
        mw[w2] = (unsigned)bal;
        mw[w2 + 1] = (unsigned)(bal >> 32);
      }
    }
  }
}

// ---------------------------------------------------------------------------
// Main. Single pass: swapped QK^T -> mask -> exp2 -> P (regs for PV, bf16
// XOR-swizzled LDS tile for write-out) -> PV MFMA -> inv_l -> attn streamed
// ROW-CONTIGUOUS (dwordx4, fill-like channel spread) -> O reduced via LDS
// overlay on already-streamed P rows 24..31.
// ---------------------------------------------------------------------------
__global__ __launch_bounds__(THREADS, 2) void attn_main(
    const float* __restrict__ q, const float* __restrict__ factor,
    const short* __restrict__ kb, const short* __restrict__ vp,
    const unsigned* __restrict__ mw, float* __restrict__ out_o,
    float* __restrict__ out_attn) {
  __shared__ __align__(16) short p_lds[QBLK * S_];   // 64 KB
  __shared__ unsigned lds_mw[QBLK * 33];             // 4.2 KB padded
  __shared__ float rs[4][QBLK];
  __shared__ float inv_l[QBLK];

  const int tid = threadIdx.x;
  const int wave = tid >> 6;
  const int lane = tid & 63;
  const int hi = lane >> 5;
  const int ln = lane & 31;

  const int blk = blockIdx.x;
  const int swz = ((blk & 7) << 8) | (blk >> 3);   // XCD-contiguous bh
  const int qt = swz & 31;
  const int bh = swz >> 5;
  const int b  = bh >> 4;
  const int q0 = qt << 5;

  const short* kp = kb + ((size_t)bh << 16);
  const short* vpp = vp + ((size_t)bh << 16);

  const unsigned* mwb = mw + ((size_t)b << 15) + ((size_t)q0 << 5);
#pragma unroll
  for (int i = tid; i < QBLK * 32; i += THREADS)
    lds_mw[(i >> 5) * 33 + (i & 31)] = mwb[i];

  // qf from f32 q, scaled by factor/8 * log2e (exp2 downstream)
  const size_t qrow = (size_t)bh * S_ + q0 + ln;
  const float fs = factor[qrow] * 0.125f * LOG2E;
  const float* qsrc = q + (qrow << 6) + (hi << 3);
  short8 qf[4];
#pragma unroll
  for (int kc = 0; kc < 4; ++kc) {
    f32x4 x0 = *(const f32x4*)(qsrc + (kc << 4));
    f32x4 x1 = *(const f32x4*)(qsrc + (kc << 4) + 4);
    short8 a;
#pragma unroll
    for (int i = 0; i < 4; ++i) { a[i] = (short)f2bfu(x0[i] * fs); a[i + 4] = (short)f2bfu(x1[i] * fs); }
    qf[kc] = a;
  }

  __syncthreads();

  f32x16 oa0, oa1;
#pragma unroll
  for (int i = 0; i < 16; ++i) { oa0[i] = 0.f; oa1[i] = 0.f; }
  float psum = 0.f;
  const int swzrow = (ln & 15) << 4;     // this lane's P-row swizzle

  // ---- pass 1: swapped QK^T -> P (LDS + regs) -> PV ----
  for (int t = wave; t < 32; t += 4) {
    // independent loads issued first
    const short* vr0 = vpp + ((size_t)ln << 10) + (t << 5) + (hi << 3);
    const short8 v00 = *(const short8*)(vr0);
    const short8 v01 = *(const short8*)(vr0 + 16);
    const short* vr1 = vr0 + (32 << 10);
    const short8 v10 = *(const short8*)(vr1);
    const short8 v11 = *(const short8*)(vr1 + 16);
    short8 kf[4];
#pragma unroll
    for (int kc = 0; kc < 4; ++kc)
      kf[kc] = *(const short8*)(kp + ((size_t)((t << 5) + ln) << 6) + (kc << 4) + (hi << 3));
    f32x16 sB;
#pragma unroll
    for (int i = 0; i < 16; ++i) sB[i] = 0.f;
#pragma unroll
    for (int kc = 0; kc < 4; ++kc)
      sB = __builtin_amdgcn_mfma_f32_32x32x16_bf16(kf[kc], qf[kc], sB, 0, 0, 0);
    const unsigned wb = lds_mw[ln * 33 + t];
    int pk[8];
#pragma unroll
    for (int j = 0; j < 8; ++j) {
      const int r0 = 2 * j;
      const int k0 = (r0 & 3) + ((r0 >> 2) << 3) + (hi << 2);
      const float p0 = ((wb >> k0) & 1u) ? __builtin_amdgcn_exp2f(sB[r0]) : 0.f;
      const float p1 = ((wb >> (k0 + 1)) & 1u) ? __builtin_amdgcn_exp2f(sB[r0 + 1]) : 0.f;
      psum += p0 + p1;
      const int pw = (int)f2bfu(p0) | ((int)f2bfu(p1) << 16);
      pk[j] = pw;
      // P -> LDS, physical byte = row*2048 + (col*2 ^ swzrow); keys (c, c+1)
      const int c = (t << 5) + k0;
      *(unsigned*)((char*)p_lds + (ln << 11) + (((c << 1)) ^ swzrow)) = (unsigned)pw;
    }
    int4v lo4 = {pk[0], pk[1], pk[2], pk[3]};
    int4v hi4 = {pk[4], pk[5], pk[6], pk[7]};
    const short8 pa0 = __builtin_bit_cast(short8, lo4);
    const short8 pa1 = __builtin_bit_cast(short8, hi4);
    oa0 = __builtin_amdgcn_mfma_f32_32x32x16_bf16(pa0, v00, oa0, 0, 0, 0);
    oa0 = __builtin_amdgcn_mfma_f32_32x32x16_bf16(pa1, v01, oa0, 0, 0, 0);
    oa1 = __builtin_amdgcn_mfma_f32_32x32x16_bf16(pa0, v10, oa1, 0, 0, 0);
    oa1 = __builtin_amdgcn_mfma_f32_32x32x16_bf16(pa1, v11, oa1, 0, 0, 0);
  }

  // ---- row sums -> inv_l (barrier also fences P writes) ----
  psum += __shfl_xor(psum, 32);
  if (lane < 32) rs[wave][ln] = psum;
  __syncthreads();
  if (tid < QBLK)
    inv_l[tid] = 1.0f / (rs[0][tid] + rs[1][tid] + rs[2][tid] + rs[3][tid]);
  __syncthreads();

  float* ap = out_attn + ((size_t)bh << 20) + ((size_t)q0 << 10);

  // ---- stream attn rows 24..31 first (their LDS space becomes o_red) ----
#pragma unroll
  for (int row = 24 + wave; row < 32; row += 4) {
    const float il = inv_l[row];
    const int srow = (row & 15) << 4;
#pragma unroll
    for (int h = 0; h < 2; ++h) {
      const int raw = (h << 10) + (lane << 4);          // logical byte in row
      const short8 pv = *(const short8*)((const char*)p_lds + (row << 11) + (raw ^ srow));
      float* dst = ap + ((size_t)row << 10) + (raw >> 1);
      f32x4 w0, w1;
#pragma unroll
      for (int i = 0; i < 4; ++i) {
        w0[i] = bfu2f((unsigned short)pv[i]) * il;
        w1[i] = bfu2f((unsigned short)pv[i + 4]) * il;
      }
      __builtin_nontemporal_store(w0, (f32x4*)dst);
      __builtin_nontemporal_store(w1, (f32x4*)(dst + 4));
    }
  }
  __syncthreads();

  // ---- O reduce in two 8 KB stages, overlaid on P rows 24..31 ----
  float (*o_red)[QBLK][32] = (float (*)[QBLK][32])(p_lds + 24 * S_);  // 16 KB
  float* op = out_o + (((size_t)bh * S_ + q0) << 6);
#pragma unroll
  for (int r = 0; r < 16; ++r) {
    const int row = (r & 3) + ((r >> 2) << 3) + (hi << 2);
    o_red[wave][row][ln] = oa0[r];
  }
  __syncthreads();
#pragma unroll
  for (int it = 0; it < 4; ++it) {
    const int idx = it * THREADS + tid;
    const int row = idx >> 5;
    const int d = idx & 31;
    const float o = o_red[0][row][d] + o_red[1][row][d] + o_red[2][row][d] + o_red[3][row][d];
    __builtin_nontemporal_store(o * inv_l[row], op + (row << 6) + d);
  }
  __syncthreads();
#pragma unroll
  for (int r = 0; r < 16; ++r) {
    const int row = (r & 3) + ((r >> 2) << 3) + (hi << 2);
    o_red[wave][row][ln] = oa1[r];
  }
  __syncthreads();
#pragma unroll
  for (int it = 0; it < 4; ++it) {
    const int idx = it * THREADS + tid;
    const int row = idx >> 5;
    const int d = idx & 31;
    const float o = o_red[0][row][d] + o_red[1][row][d] + o_red[2][row][d] + o_red[3][row][d];
    __builtin_nontemporal_store(o * inv_l[row], op + (row << 6) + 32 + d);
  }

  // ---- stream attn rows 0..23 (LDS untouched by o_red) ----
  for (int row = wave; row < 24; row += 4) {
    const float il = inv_l[row];
    const int srow = (row & 15) << 4;
#pragma unroll
    for (int h = 0; h < 2; ++h) {
      const int raw = (h << 10) + (lane << 4);
      const short8 pv = *(const short8*)((const char*)p_lds + (row << 11) + (raw ^ srow));
      float* dst = ap + ((size_t)row << 10) + (raw >> 1);
      f32x4 w0, w1;
#pragma unroll
      for (int i = 0; i < 4; ++i) {
        w0[i] = bfu2f((unsigned short)pv[i]) * il;
        w1[i] = bfu2f((unsigned short)pv[i + 4]) * il;
      }
      __builtin_nontemporal_store(w0, (f32x4*)dst);
      __builtin_nontemporal_store(w1, (f32x4*)(dst + 4));
    }
  }
}

extern "C" void kernel_launch(void* const* d_in, const int* in_sizes, int n_in,
                              void* d_out, int out_size, void* d_ws, size_t ws_size,
                              hipStream_t stream) {
  (void)in_sizes; (void)n_in; (void)ws_size; (void)out_size;
  const float* q = (const float*)d_in[0];
  const float* k = (const float*)d_in[1];
  const float* v = (const float*)d_in[2];
  const float* f = (const float*)d_in[3];
  const int*   m = (const int*)d_in[4];
  float* out_o    = (float*)d_out;
  float* out_attn = out_o + (size_t)4 * 16 * 1024 * 64;

  short* kbuf = (short*)d_ws;                       // 8 MB
  short* vbuf = kbuf + 4194304;                     // 8 MB
  unsigned* mwbuf = (unsigned*)(vbuf + 4194304);    // 512 KB

  prep<<<5120, THREADS, 0, stream>>>(k, v, m, kbuf, vbuf, mwbuf);
  attn_main<<<2048, THREADS, 0, stream>>>(q, f, kbuf, vbuf, mwbuf, out_o, out_attn);
}

// Round 7
// 83.551 us; speedup vs baseline: 1.6611x; 1.6611x over previous
//
#include <hip/hip_runtime.h>
#include <hip/hip_bf16.h>

#define S_ 1024
#define D_ 64
#define QBLK 32
#define THREADS 256
#define LOG2E 1.44269504088896f

typedef __attribute__((ext_vector_type(8)))  short short8;
typedef __attribute__((ext_vector_type(4)))  int   int4v;
typedef __attribute__((ext_vector_type(16))) float f32x16;
typedef __attribute__((ext_vector_type(4)))  float f32x4;

__device__ __forceinline__ unsigned short f2bfu(float x) {
  return __builtin_bit_cast(unsigned short, __float2bfloat16(x));
}

// ---------------------------------------------------------------------------
// prep: fragment-ordered K and V so ALL main-kernel inner-loop loads are
// lane-coalesced 1KB dwordx4.
//  [0,2048)     kperm[bh][t][kc][lane] : 8 bf16 = K[bh][t*32+(lane&31)]
//                                         [kc*16+(lane>>5)*8 .. +8)
//  [2048,4096)  vperm[bh][t][h][lane]  : 8 bf16, elem i =
//                 V[bh][t*32+(h&1)*16+(i&3)+((i>>2)<<3)+(lane>>5)*4]
//                  [((h&2)<<4)+(lane&31)]
//  [4096,6144)  mw bit-pack via wave ballot, grid-strided x8
// ---------------------------------------------------------------------------
__global__ __launch_bounds__(THREADS) void prep(
    const float* __restrict__ k, const float* __restrict__ v,
    const int* __restrict__ mask, short* __restrict__ kperm,
    short* __restrict__ vperm, unsigned* __restrict__ mw) {
  const int blk = blockIdx.x;
  const int tid = threadIdx.x;
  if (blk < 2048) {
    const int gid = blk * THREADS + tid;       // (bh,t,kc,lane) chunk
    const int lane = gid & 63;
    const int kc = (gid >> 6) & 3;
    const int t = (gid >> 8) & 31;
    const int bh = gid >> 13;
    const int ln = lane & 31, hi = lane >> 5;
    const float* src = k + ((((size_t)(bh << 10) + (t << 5) + ln)) << 6) + (kc << 4) + (hi << 3);
    f32x4 x0 = *(const f32x4*)src;
    f32x4 x1 = *(const f32x4*)(src + 4);
    short8 o;
#pragma unroll
    for (int i = 0; i < 4; ++i) { o[i] = (short)f2bfu(x0[i]); o[i + 4] = (short)f2bfu(x1[i]); }
    *(short8*)(kperm + ((size_t)gid << 3)) = o;
  } else if (blk < 4096) {
    const int gid = (blk - 2048) * THREADS + tid;   // (bh,t,h,lane) chunk
    const int lane = gid & 63;
    const int h = (gid >> 6) & 3;
    const int t = (gid >> 8) & 31;
    const int bh = gid >> 13;
    const int ln = lane & 31, hi = lane >> 5;
    const int dcol = ((h & 2) << 4) + ln;
    const float* vb = v + ((size_t)bh << 16) + dcol;
    short8 o;
#pragma unroll
    for (int i = 0; i < 8; ++i) {
      const int key = (t << 5) + ((h & 1) << 4) + (i & 3) + ((i >> 2) << 3) + (hi << 2);
      o[i] = (short)f2bfu(vb[(size_t)key << 6]);
    }
    *(short8*)(vperm + ((size_t)gid << 3)) = o;
  } else {
    const int g = blk - 4096;
#pragma unroll
    for (int it = 0; it < 8; ++it) {
      const size_t base = ((size_t)g * 8 + it) * THREADS + tid;
      const unsigned long long bal = __ballot(mask[base] != 0);
      if ((tid & 63) == 0) {
        const size_t w2 = base >> 5;
        mw[w2] = (unsigned)bal;
        mw[w2 + 1] = (unsigned)(bal >> 32);
      }
    }
  }
}

// ---------------------------------------------------------------------------
// Main. Block = (bh, 32 q-rows), XCD-swizzled. TWO barriers total.
// Pass 1: swapped QK^T (coalesced kperm frags) -> mask -> exp2 -> psum + PV
//         (coalesced vperm frags). Write rs + o_red to LDS -> barrier.
// Epilogue: O summed + stored (inv_l recomputed from rs broadcasts).
// Pass 2: normal QK^T (kperm L2-hot), exp2 * invr, nontemporal stores.
// ---------------------------------------------------------------------------
__global__ __launch_bounds__(THREADS, 3) void attn_main(
    const float* __restrict__ q, const float* __restrict__ factor,
    const short* __restrict__ kperm, const short* __restrict__ vperm,
    const unsigned* __restrict__ mw, float* __restrict__ out_o,
    float* __restrict__ out_attn) {
  __shared__ float o_red[4][QBLK][D_];     // 32 KB
  __shared__ unsigned lds_mw[QBLK * 33];   // 4.2 KB padded
  __shared__ float rs[4][QBLK];

  const int tid = threadIdx.x;
  const int wave = tid >> 6;
  const int lane = tid & 63;
  const int hi = lane >> 5;
  const int ln = lane & 31;

  const int blk = blockIdx.x;
  const int swz = ((blk & 7) << 8) | (blk >> 3);   // XCD-contiguous bh
  const int qt = swz & 31;
  const int bh = swz >> 5;
  const int b  = bh >> 4;
  const int q0 = qt << 5;

  const short* kpb = kperm + ((size_t)bh << 16);
  const short* vpb = vperm + ((size_t)bh << 16);

  const unsigned* mwb = mw + ((size_t)b << 15) + ((size_t)q0 << 5);
#pragma unroll
  for (int i = tid; i < QBLK * 32; i += THREADS)
    lds_mw[(i >> 5) * 33 + (i & 31)] = mwb[i];

  // qf from f32 q, scaled by factor/8*log2e (one-time gather, acceptable)
  const size_t qrow = (size_t)bh * S_ + q0 + ln;
  const float fs = factor[qrow] * 0.125f * LOG2E;
  const float* qsrc = q + (qrow << 6) + (hi << 3);
  short8 qf[4];
#pragma unroll
  for (int kc = 0; kc < 4; ++kc) {
    f32x4 x0 = *(const f32x4*)(qsrc + (kc << 4));
    f32x4 x1 = *(const f32x4*)(qsrc + (kc << 4) + 4);
    short8 a;
#pragma unroll
    for (int i = 0; i < 4; ++i) { a[i] = (short)f2bfu(x0[i] * fs); a[i + 4] = (short)f2bfu(x1[i] * fs); }
    qf[kc] = a;
  }

  __syncthreads();   // barrier 1: lds_mw ready

  f32x16 oa0, oa1;
#pragma unroll
  for (int i = 0; i < 16; ++i) { oa0[i] = 0.f; oa1[i] = 0.f; }
  float psum = 0.f;

  // ---- pass 1: swapped QK^T + PV, all frag loads coalesced 1KB ----
  for (int t = wave; t < 32; t += 4) {
    const short* kt = kpb + ((size_t)t << 11) + (lane << 3);
    const short* vt = vpb + ((size_t)t << 11) + (lane << 3);
    short8 kf[4];
#pragma unroll
    for (int kc = 0; kc < 4; ++kc) kf[kc] = *(const short8*)(kt + (kc << 9));
    const short8 v00 = *(const short8*)(vt);
    const short8 v01 = *(const short8*)(vt + 512);
    const short8 v10 = *(const short8*)(vt + 1024);
    const short8 v11 = *(const short8*)(vt + 1536);
    f32x16 sB;
#pragma unroll
    for (int i = 0; i < 16; ++i) sB[i] = 0.f;
#pragma unroll
    for (int kc = 0; kc < 4; ++kc)
      sB = __builtin_amdgcn_mfma_f32_32x32x16_bf16(kf[kc], qf[kc], sB, 0, 0, 0);
    const unsigned wb = lds_mw[ln * 33 + t];
    int pk[8];
#pragma unroll
    for (int j = 0; j < 8; ++j) {
      const int r0 = 2 * j;
      const int k0 = (r0 & 3) + ((r0 >> 2) << 3) + (hi << 2);
      const float p0 = ((wb >> k0) & 1u) ? __builtin_amdgcn_exp2f(sB[r0]) : 0.f;
      const float p1 = ((wb >> (k0 + 1)) & 1u) ? __builtin_amdgcn_exp2f(sB[r0 + 1]) : 0.f;
      psum += p0 + p1;
      pk[j] = (int)f2bfu(p0) | ((int)f2bfu(p1) << 16);
    }
    int4v lo4 = {pk[0], pk[1], pk[2], pk[3]};
    int4v hi4 = {pk[4], pk[5], pk[6], pk[7]};
    const short8 pa0 = __builtin_bit_cast(short8, lo4);
    const short8 pa1 = __builtin_bit_cast(short8, hi4);
    oa0 = __builtin_amdgcn_mfma_f32_32x32x16_bf16(pa0, v00, oa0, 0, 0, 0);
    oa0 = __builtin_amdgcn_mfma_f32_32x32x16_bf16(pa1, v01, oa0, 0, 0, 0);
    oa1 = __builtin_amdgcn_mfma_f32_32x32x16_bf16(pa0, v10, oa1, 0, 0, 0);
    oa1 = __builtin_amdgcn_mfma_f32_32x32x16_bf16(pa1, v11, oa1, 0, 0, 0);
  }

  // ---- rs + o_red, ONE barrier ----
  psum += __shfl_xor(psum, 32);
  if (lane < 32) rs[wave][ln] = psum;
#pragma unroll
  for (int r = 0; r < 16; ++r) {
    const int row = (r & 3) + ((r >> 2) << 3) + (hi << 2);
    o_red[wave][row][ln] = oa0[r];
    o_red[wave][row][ln + 32] = oa1[r];
  }
  __syncthreads();   // barrier 2: rs + o_red ready

  // ---- O store (row uniform per wave per it; rs reads broadcast) ----
  float* op = out_o + (((size_t)bh * S_ + q0) << 6);
#pragma unroll
  for (int it = 0; it < 8; ++it) {
    const int row = (it << 2) + wave;
    const float il = 1.0f / (rs[0][row] + rs[1][row] + rs[2][row] + rs[3][row]);
    const float o = o_red[0][row][lane] + o_red[1][row][lane] +
                    o_red[2][row][lane] + o_red[3][row][lane];
    __builtin_nontemporal_store(o * il, op + (row << 6) + lane);
  }

  // ---- per-thread inv_l for pass-2 rows (broadcast rs reads) ----
  float invr[16];
#pragma unroll
  for (int r = 0; r < 16; ++r) {
    const int row = (r & 3) + ((r >> 2) << 3) + (hi << 2);
    invr[r] = 1.0f / (rs[0][row] + rs[1][row] + rs[2][row] + rs[3][row]);
  }

  // ---- pass 2: recompute S (kperm L2-hot), stream normalized attn ----
  float* ap = out_attn + ((size_t)bh << 20) + ((size_t)q0 << 10);
  for (int t = wave; t < 32; t += 4) {
    const short* kt = kpb + ((size_t)t << 11) + (lane << 3);
    short8 kf[4];
#pragma unroll
    for (int kc = 0; kc < 4; ++kc) kf[kc] = *(const short8*)(kt + (kc << 9));
    f32x16 sA;
#pragma unroll
    for (int i = 0; i < 16; ++i) sA[i] = 0.f;
#pragma unroll
    for (int kc = 0; kc < 4; ++kc)
      sA = __builtin_amdgcn_mfma_f32_32x32x16_bf16(qf[kc], kf[kc], sA, 0, 0, 0);
#pragma unroll
    for (int r = 0; r < 16; ++r) {
      const int row = (r & 3) + ((r >> 2) << 3) + (hi << 2);
      const unsigned w = lds_mw[row * 33 + t];
      const float p = ((w >> ln) & 1u) ? __builtin_amdgcn_exp2f(sA[r]) * invr[r] : 0.f;
      __builtin_nontemporal_store(p, ap + ((size_t)row << 10) + (t << 5) + ln);
    }
  }
}

extern "C" void kernel_launch(void* const* d_in, const int* in_sizes, int n_in,
                              void* d_out, int out_size, void* d_ws, size_t ws_size,
                              hipStream_t stream) {
  (void)in_sizes; (void)n_in; (void)ws_size; (void)out_size;
  const float* q = (const float*)d_in[0];
  const float* k = (const float*)d_in[1];
  const float* v = (const float*)d_in[2];
  const float* f = (const float*)d_in[3];
  const int*   m = (const int*)d_in[4];
  float* out_o    = (float*)d_out;
  float* out_attn = out_o + (size_t)4 * 16 * 1024 * 64;

  short* kpbuf = (short*)d_ws;                      // 8 MB
  short* vpbuf = kpbuf + 4194304;                   // 8 MB
  unsigned* mwbuf = (unsigned*)(vpbuf + 4194304);   // 512 KB

  prep<<<6144, THREADS, 0, stream>>>(k, v, m, kpbuf, vpbuf, mwbuf);
  attn_main<<<2048, THREADS, 0, stream>>>(q, f, kpbuf, vpbuf, mwbuf, out_o, out_attn);
}